// Round 15
// baseline (203.168 us; speedup 1.0000x reference)
//
#include <hip/hip_runtime.h>
#include <hip/hip_bf16.h>
#include <math.h>

// B=8, C=256, H=W=64, G=4, K=3, KK=9, Cg=64
// Round 24: base = r22 (193.5us). k_offconv tap loop m-split across waves:
// wave wv owns m-tiles {2wv, 2wv+1} (wave3: {6}) for ALL 64 pixels (B-frags
// read from the shared p_s window). Per phase: <=2 af loads (was 7) ->
// block weight fetch /4 (4.0 -> 1.0 MB/CU; was 57% of per-CU L2 share).
// No barriers added; accumulation chain per output element unchanged
// => bit-identical. 2-row blocks, grid 1024 (r17/r22 best config).
// k_dcn keeps r22 form (47.2us, at its divergent-gather floor).
// ws layout (bytes):
//   wpart bf16 [4][8][108][4096] @ 0          (28,311,552)
//   wo_a  bf16 [4][9][2][7][64][8] @ 28,311,552 (516,096)  fragment-major
//   wd_a  bf16 [4][9][64][64]    @ 28,827,648 (294,912)   [g][tap][co][cl]
//   x2    bf16 [256][4356][8]    @ 29,122,560 (17,842,176)
// total 46,964,736 B (< proven 48.3 MB)

typedef __attribute__((ext_vector_type(4))) short s16x4;
typedef __attribute__((ext_vector_type(8))) short s16x8;
typedef __attribute__((ext_vector_type(4))) float f32x4;

union S8 { s16x8 v; s16x4 h[2]; };
union S8U { s16x8 v; unsigned u[4]; };

__device__ __forceinline__ s16x8 ld8(const short* p) {
  S8 r;
  r.h[0] = *(const s16x4*)p;
  r.h[1] = *(const s16x4*)(p + 4);
  return r.v;
}

__device__ __forceinline__ unsigned short bfr(float v) {  // RNE to bf16
  unsigned u = __float_as_uint(v);
  u = (u + 0x7FFFu + ((u >> 16) & 1u)) >> 16;
  return (unsigned short)u;
}
__device__ __forceinline__ float bff(unsigned short s) {
  return __uint_as_float(((unsigned)s) << 16);
}
__device__ __forceinline__ float bf(short s) {
  return __uint_as_float(((unsigned)(unsigned short)s) << 16);
}
__device__ __forceinline__ unsigned cvtpk(float lo, float hi) {  // RNE pair
  union { __hip_bfloat162 b; unsigned u; } cv;
  cv.b = __float22bfloat162_rn(make_float2(lo, hi));
  return cv.u;
}

__global__ __launch_bounds__(256) void k_prep(
    const float* __restrict__ w_off, const float* __restrict__ w_dcn,
    short* __restrict__ wo_a, short* __restrict__ wd_a) {
  int i = blockIdx.x * 256 + threadIdx.x;
  const int n1 = 112 * 2304;  // = 258048 = 4*9*2*7*64*8
  if (i < n1) {
    // fragment-major: i = ((((part*9+tap)*2+s)*7+mt)*64 + lane)*8 + e
    int e = i & 7;
    int t1 = i >> 3;
    int lane = t1 & 63;
    int t2 = t1 >> 6;
    int mt = t2 % 7;
    int t3 = t2 / 7;
    int s = t3 & 1;
    int t4 = t3 >> 1;
    int tap = t4 % 9;
    int part = t4 / 9;
    int co = mt * 16 + (lane & 15);
    int ch = part * 64 + s * 32 + (lane >> 4) * 8 + e;
    float v = (co < 108) ? w_off[(co * 256 + ch) * 9 + tap] : 0.f;
    wo_a[i] = (short)bfr(v);
  } else {
    int j = i - n1;  // exactly 147456 remaining threads (grid 1584*256)
    int g = j / 36864, r = j % 36864;
    // layout: [g][tap][co][cl]
    int tap = r >> 12;  // r / 4096
    int q = r & 4095;
    int co = q >> 6, cl = q & 63;
    wd_a[j] = (short)bfr(w_dcn[((g * 64 + co) * 64 + cl) * 9 + tap]);
  }
}

// x -> chunked bf16 NHWC with zero halo.
// interior: thread = (b, c2, pixel); border: zero 16B slots.
__global__ __launch_bounds__(256) void k_x2(
    const float* __restrict__ x, short* __restrict__ x2) {
  int id = blockIdx.x * 256 + threadIdx.x;
  const int n1 = 8 * 32 * 4096;  // 1,048,576 interior items
  if (id < n1) {
    int pc = id & 4095;
    int c2 = (id >> 12) & 31;
    int b = id >> 17;
    int h = pc >> 6, w = pc & 63;
    const float* xp = x + ((size_t)(b * 256 + c2 * 8)) * 4096 + pc;
    short* o = x2 + ((size_t)(b * 32 + c2) * 4356 + (h + 1) * 66 + (w + 1)) * 8;
    s16x4 v0, v1;
#pragma unroll
    for (int i = 0; i < 4; ++i) {
      v0[i] = (short)bfr(xp[(size_t)i * 4096]);
      v1[i] = (short)bfr(xp[(size_t)(i + 4) * 4096]);
    }
    *(s16x4*)o = v0;
    *(s16x4*)(o + 4) = v1;
  } else {
    int j = id - n1;  // grid sized exactly: j < 256*260
    int plane = j / 260, r = j % 260;
    int h, w;
    if (r < 66) { h = 0; w = r; }
    else if (r < 132) { h = 65; w = r - 66; }
    else if (r < 196) { h = r - 131; w = 0; }
    else { h = r - 195; w = 65; }
    short* o = x2 + ((size_t)plane * 4356 + h * 66 + w) * 8;
    s16x4 z = {0, 0, 0, 0};
    *(s16x4*)o = z;
    *(s16x4*)(o + 4) = z;
  }
}

// Offset conv, bf16 MFMA, K-split by channel-quarter, XCD-pinned slices.
// Round 24: 2-row blocks, grid 1024; waves m-split. Wave wv computes
// m-tiles {2wv, 2wv+1} (wave3: {6}) for all 64 pixels x 2 rows; per
// (tap,s) it loads only its own af fragments (<=2 contiguous 1KiB wave
// loads) -> one weight copy per block instead of four.
__global__ __launch_bounds__(256) void k_offconv(
    const short* __restrict__ x2, const short* __restrict__ wo_a,
    const float* __restrict__ b_off, short* __restrict__ wpart) {
  __shared__ short p_s[4 * 66 * 68];  // [winrow 0..3][pix 0..65][64 ch + 4 pad]
  int bi = blockIdx.x;  // 1024
  int xcd = bi & 7;
  int j = bi >> 3;                // 0..127
  int slice = xcd * 4 + (j & 3);  // 0..31, pinned to xcd
  int h0 = (j >> 2) * 2;          // 0,2,...,62
  int part = slice >> 3, b = slice & 7;
  int tid = threadIdx.x;
  int lane = tid & 63, wv = tid >> 6;
  int quad = lane >> 4, l15 = lane & 15;

  int mt0 = 2 * wv;          // wave's first m-tile
  bool two = (wv < 3);       // waves 0..2 own 2 m-tiles; wave 3 owns mt=6

  f32x4 zero4 = {0.f, 0.f, 0.f, 0.f};
  f32x4 acc[2][2][4];  // [mtsub][row][pixgroup]
#pragma unroll
  for (int a = 0; a < 2; ++a)
#pragma unroll
    for (int r = 0; r < 2; ++r)
#pragma unroll
      for (int p = 0; p < 4; ++p) acc[a][r][p] = zero4;

  // planes for this block's 64 channels: (b*32 + part*8 + ck), ck = 0..7
  const short* x2b = x2 + (size_t)(b * 32 + part * 8) * 34848;
  // fragment-major weight base for this part: [tap][s][mt][lane][8]
  const short* wfrag = wo_a + (size_t)part * 64512 + lane * 8;

  // Stage the 4-row x 66-col window once: 2112 x 16B chunks (8.25/thread).
  for (int it = tid; it < 2112; it += 256) {
    int ck = it / 264;
    int rp = it - ck * 264;  // rp = winrow*66 + pix
    const short* src = x2b + (size_t)ck * 34848 + ((size_t)h0 * 66 + rp) * 8;
    S8 v;
    v.v = *(const s16x8*)src;  // 16B aligned
    short* dst = &p_s[rp * 68 + ck * 8];
    *(s16x4*)dst = v.h[0];
    *(s16x4*)(dst + 4) = v.h[1];
  }
  __syncthreads();

#pragma unroll
  for (int tap = 0; tap < 9; ++tap) {
    int ky = tap / 3, kx = tap % 3;
#pragma unroll
    for (int s = 0; s < 2; ++s) {
      int k0 = 32 * s + quad * 8;
      const short* wb = wfrag + (size_t)(tap * 2 + s) * 3584;
      s16x8 af0 = *(const s16x8*)(wb + (size_t)mt0 * 512);
      s16x8 af1 = af0;
      if (two) af1 = *(const s16x8*)(wb + (size_t)(mt0 + 1) * 512);
#pragma unroll
      for (int rr = 0; rr < 2; ++rr) {
#pragma unroll
        for (int pg = 0; pg < 4; ++pg) {
          // pixel nb = pg*16 + l15; tap (ky,kx): padded (h0+rr+ky, nb+kx)
          s16x8 bf_f = ld8(&p_s[((rr + ky) * 66 + pg * 16 + l15 + kx) * 68 + k0]);
          acc[0][rr][pg] =
              __builtin_amdgcn_mfma_f32_16x16x32_bf16(af0, bf_f, acc[0][rr][pg], 0, 0, 0);
          if (two)
            acc[1][rr][pg] =
                __builtin_amdgcn_mfma_f32_16x16x32_bf16(af1, bf_f, acc[1][rr][pg], 0, 0, 0);
        }
      }
    }
  }

  short* wp = wpart + ((size_t)part * 8 + b) * 108 * 4096;
#pragma unroll
  for (int ms = 0; ms < 2; ++ms) {
    if (ms == 0 || two) {
      int mt = mt0 + ms;
#pragma unroll
      for (int rr = 0; rr < 2; ++rr) {
#pragma unroll
        for (int pg = 0; pg < 4; ++pg) {
#pragma unroll
          for (int r = 0; r < 4; ++r) {
            int co = 16 * mt + quad * 4 + r;
            if (co < 108) {
              float v = acc[ms][rr][pg][r] + (part == 0 ? b_off[co] : 0.f);
              wp[(size_t)co * 4096 + (h0 + rr) * 64 + pg * 16 + l15] = (short)bfr(v);
            }
          }
        }
      }
    }
  }
}

// DCN, bf16 MFMA, XCD-pinned (b,g) groups.
// Round 22 form: r17 structure (1-row, grid 2048, wlds double-buffered
// staging, 1 barrier/tap, corner prefetch) + cvt_pk pair rounding.
__global__ __launch_bounds__(256) void k_dcn(
    const short* __restrict__ x2, const short* __restrict__ wpart,
    const short* __restrict__ wd_a, const float* __restrict__ b_dcn,
    float* __restrict__ dcn) {
  __shared__ float4 prm[9][64];      // (py, pxf, m, -) per (tap, px)
  __shared__ short wlds[2][64][72];  // [buf][co][64k + 8 pad]

  int bi = blockIdx.x;  // 2048
  int xcd = bi & 7;
  int j = bi >> 3;
  int grp = xcd * 4 + (j & 3);  // 0..31, pinned to xcd
  int h = j >> 2;               // 0..63
  int b = grp >> 2, g = grp & 3;
  int tid = threadIdx.x;
  int lane = tid & 63, wv = tid >> 6;
  int quad = lane >> 4, l15 = lane & 15;
  int px = 16 * wv + l15;  // pixel this lane samples AND owns as output column

  f32x4 zero4 = {0.f, 0.f, 0.f, 0.f};
  f32x4 acc[4];
#pragma unroll
  for (int i = 0; i < 4; ++i) acc[i] = zero4;

  const short* x2g = x2 + (size_t)(b * 32 + g * 8) * 34848;
  const short* plA = x2g + (size_t)quad * 34848;        // chans 8q..8q+7  (s=0)
  const short* plB = x2g + (size_t)(quad + 4) * 34848;  // chans 32+8q..+7 (s=1)
  const short* wd_g = wd_a + (size_t)g * 36864;         // [tap][co][64]

  // weight staging role: thread stages 32B of the tap slice (coalesced)
  int co_w = tid >> 2, kp_w = (tid & 3) * 16;

  // ---- Prologue: stage tap-0 weights + offset/mask params; one barrier ----
  {
    const short* wsrc = wd_g + co_w * 64 + kp_w;
    s16x8 w0 = *(const s16x8*)wsrc;
    s16x8 w1 = *(const s16x8*)(wsrc + 8);
    *(s16x8*)&wlds[0][co_w][kp_w] = w0;
    *(s16x8*)&wlds[0][co_w][kp_w + 8] = w1;
  }
  for (int i = tid; i < 576; i += 256) {
    int c = i >> 6, pxa = i & 63;
    int sp = h * 64 + pxa;
    int co_y = (g * 9 + c) * 2;
    float oy = 0.f, ox = 0.f, mz = 0.f;
#pragma unroll
    for (int p4 = 0; p4 < 4; ++p4) {
      const short* wp = wpart + ((size_t)p4 * 8 + b) * 108 * 4096;
      oy += bff((unsigned short)wp[(size_t)co_y * 4096 + sp]);
      ox += bff((unsigned short)wp[(size_t)(co_y + 1) * 4096 + sp]);
      mz += bff((unsigned short)wp[(size_t)(72 + g * 9 + c) * 4096 + sp]);
    }
    float m = 1.f / (1.f + __expf(-mz));
    float py = (float)h + (float)(c / 3 - 1) + oy;
    float pxf = (float)pxa + (float)(c % 3 - 1) + ox;
    prm[c][pxa] = make_float4(py, pxf, m, 0.f);
  }
  __syncthreads();  // covers prm + wlds[0]

  // corner registers, double-buffered across taps
  s16x8 cA[2][4], cB[2][4];
  float4 wts[2];

  auto stage = [&](int c, int st) {
    float4 pr = prm[c][px];
    float py = pr.x, pxf = pr.y, m = pr.z;
    float y0 = floorf(py), x0 = floorf(pxf);
    float wy1 = py - y0, wy0 = 1.f - wy1;
    float wx1 = pxf - x0, wx0 = 1.f - wx1;
    int y0i = (int)y0, x0i = (int)x0;
    int y1i = y0i + 1, x1i = x0i + 1;
    bool vy0 = (y0i >= 0) & (y0i < 64), vy1 = (y1i >= 0) & (y1i < 64);
    bool vx0 = (x0i >= 0) & (x0i < 64), vx1 = (x1i >= 0) & (x1i < 64);
    int cy0 = min(max(y0i, 0), 63) + 1, cy1 = min(max(y1i, 0), 63) + 1;
    int cx0 = min(max(x0i, 0), 63) + 1, cx1 = min(max(x1i, 0), 63) + 1;
    int i00 = cy0 * 66 + cx0, i01 = cy0 * 66 + cx1;
    int i10 = cy1 * 66 + cx0, i11 = cy1 * 66 + cx1;
    wts[st] = make_float4((vy0 && vx0) ? wy0 * wx0 * m : 0.f,
                          (vy0 && vx1) ? wy0 * wx1 * m : 0.f,
                          (vy1 && vx0) ? wy1 * wx0 * m : 0.f,
                          (vy1 && vx1) ? wy1 * wx1 * m : 0.f);
    cA[st][0] = *(const s16x8*)(plA + (size_t)i00 * 8);  // 16B aligned
    cA[st][1] = *(const s16x8*)(plA + (size_t)i01 * 8);
    cA[st][2] = *(const s16x8*)(plA + (size_t)i10 * 8);
    cA[st][3] = *(const s16x8*)(plA + (size_t)i11 * 8);
    cB[st][0] = *(const s16x8*)(plB + (size_t)i00 * 8);
    cB[st][1] = *(const s16x8*)(plB + (size_t)i01 * 8);
    cB[st][2] = *(const s16x8*)(plB + (size_t)i10 * 8);
    cB[st][3] = *(const s16x8*)(plB + (size_t)i11 * 8);
  };

  stage(0, 0);
#pragma unroll
  for (int c = 0; c < 9; ++c) {
    int cur = c & 1;                   // compile-time after unroll
    // issue next-tap weight loads (coalesced) + corner gathers, all in flight
    s16x8 wn0, wn1;
    if (c < 8) {
      const short* wsrc = wd_g + (size_t)(c + 1) * 4096 + co_w * 64 + kp_w;
      wn0 = *(const s16x8*)wsrc;
      wn1 = *(const s16x8*)(wsrc + 8);
      stage(c + 1, cur ^ 1);
    }

    float4 w = wts[cur];
    // bilinear combine (same math/order as r17), cvt_pk pair rounding
    S8U bf0, bf1;
#pragma unroll
    for (int i2 = 0; i2 < 4; ++i2) {
      int e0 = 2 * i2, e1 = 2 * i2 + 1;
      float vA0 = w.x * bf(cA[cur][0][e0]) + w.y * bf(cA[cur][1][e0]) +
                  w.z * bf(cA[cur][2][e0]) + w.w * bf(cA[cur][3][e0]);
      float vA1 = w.x * bf(cA[cur][0][e1]) + w.y * bf(cA[cur][1][e1]) +
                  w.z * bf(cA[cur][2][e1]) + w.w * bf(cA[cur][3][e1]);
      float vB0 = w.x * bf(cB[cur][0][e0]) + w.y * bf(cB[cur][1][e0]) +
                  w.z * bf(cB[cur][2][e0]) + w.w * bf(cB[cur][3][e0]);
      float vB1 = w.x * bf(cB[cur][0][e1]) + w.y * bf(cB[cur][1][e1]) +
                  w.z * bf(cB[cur][2][e1]) + w.w * bf(cB[cur][3][e1]);
      bf0.u[i2] = cvtpk(vA0, vA1);
      bf1.u[i2] = cvtpk(vB0, vB1);
    }

#pragma unroll
    for (int mt = 0; mt < 4; ++mt) {  // s = 0: k0 = quad*8
      s16x8 af = *(const s16x8*)&wlds[cur][16 * mt + l15][quad * 8];
      acc[mt] = __builtin_amdgcn_mfma_f32_16x16x32_bf16(af, bf0.v, acc[mt], 0, 0, 0);
    }
#pragma unroll
    for (int mt = 0; mt < 4; ++mt) {  // s = 1: k0 = 32 + quad*8
      s16x8 af = *(const s16x8*)&wlds[cur][16 * mt + l15][32 + quad * 8];
      acc[mt] = __builtin_amdgcn_mfma_f32_16x16x32_bf16(af, bf1.v, acc[mt], 0, 0, 0);
    }

    if (c < 8) {
      // write next tap's weights; prior readers of this buffer passed the
      // previous iteration's barrier already.
      *(s16x8*)&wlds[cur ^ 1][co_w][kp_w] = wn0;
      *(s16x8*)&wlds[cur ^ 1][co_w][kp_w + 8] = wn1;
      __syncthreads();
    }
  }

  int nb = px;
#pragma unroll
  for (int mt = 0; mt < 4; ++mt) {
#pragma unroll
    for (int r = 0; r < 4; ++r) {
      int co = 16 * mt + quad * 4 + r;
      dcn[(((size_t)b * 256 + g * 64 + co) * 64 + h) * 64 + nb] =
          acc[mt][r] + b_dcn[g * 64 + co];
    }
  }
}

// LayerNorm over C + sigmoid + gate. dcn == out (in-place safe).
// Round 17 form: one-pass, 64 channel values cached in registers.
__global__ __launch_bounds__(256) void k_ln(
    const float* __restrict__ dcn, const float* __restrict__ x,
    const float* __restrict__ gamma, const float* __restrict__ beta,
    float* __restrict__ out) {
  __shared__ float red_s[4][64];
  __shared__ float red_q[4][64];
  int px = threadIdx.x & 63;
  int part = threadIdx.x >> 6;
  int p = blockIdx.x * 64 + px;  // 32768 pixels
  int b = p >> 12, hw = p & 4095;
  const float* ob = dcn + (size_t)b * 256 * 4096 + hw;
  const float* xb = x + (size_t)b * 256 * 4096 + hw;
  float* yb = out + (size_t)b * 256 * 4096 + hw;
  int c0 = part * 64;
  float v[64];
  float s = 0.f, s2 = 0.f;
#pragma unroll
  for (int i = 0; i < 64; ++i) {
    v[i] = ob[(c0 + i) * 4096];
    s += v[i];
    s2 += v[i] * v[i];
  }
  red_s[part][px] = s;
  red_q[part][px] = s2;
  __syncthreads();
  s = red_s[0][px] + red_s[1][px] + red_s[2][px] + red_s[3][px];
  s2 = red_q[0][px] + red_q[1][px] + red_q[2][px] + red_q[3][px];
  float mu = s * (1.f / 256.f);
  float var = s2 * (1.f / 256.f) - mu * mu;
  float rs = rsqrtf(var + 1e-5f);
#pragma unroll
  for (int i = 0; i < 64; ++i) {
    int c = c0 + i;
    float nrm = (v[i] - mu) * rs * gamma[c] + beta[c];
    float attn = 1.f / (1.f + __expf(-nrm));
    yb[c * 4096] = xb[c * 4096] * attn;
  }
}

extern "C" void kernel_launch(void* const* d_in, const int* in_sizes, int n_in,
                              void* d_out, int out_size, void* d_ws,
                              size_t ws_size, hipStream_t stream) {
  const float* x = (const float*)d_in[0];
  const float* w_off = (const float*)d_in[1];
  const float* b_off = (const float*)d_in[2];
  const float* w_dcn = (const float*)d_in[3];
  const float* b_dcn = (const float*)d_in[4];
  const float* gamma = (const float*)d_in[5];
  const float* beta = (const float*)d_in[6];
  float* out = (float*)d_out;
  char* wsb = (char*)d_ws;

  short* wpart = (short*)wsb;              // 28,311,552 B
  short* wo_a = (short*)(wsb + 28311552);  // 516,096 B
  short* wd_a = (short*)(wsb + 28827648);  // 294,912 B
  short* x2 = (short*)(wsb + 29122560);    // 17,842,176 B
  float* dcnb = out;                       // d_out doubles as dcn scratch

  k_prep<<<1584, 256, 0, stream>>>(w_off, w_dcn, wo_a, wd_a);
  k_x2<<<4356, 256, 0, stream>>>(x, x2);
  k_offconv<<<1024, 256, 0, stream>>>(x2, wo_a, b_off, wpart);
  k_dcn<<<2048, 256, 0, stream>>>(x2, wpart, wd_a, b_dcn, dcnb);
  k_ln<<<512, 256, 0, stream>>>(dcnb, x, gamma, beta, out);
}

// Round 16
// 202.127 us; speedup vs baseline: 1.0052x; 1.0052x over previous
//
#include <hip/hip_runtime.h>
#include <hip/hip_bf16.h>
#include <math.h>

// B=8, C=256, H=W=64, G=4, K=3, KK=9, Cg=64
// Round 25: base = r22 (193.5us best). Sole change: k_ln re-tiled for
// occupancy. Old: 512 blocks (2/CU, 8 waves/CU) -- a ~100MB memory-bound
// kernel capped at 25% occupancy ≈ 2.5-3 TB/s ≈ 35-40us (largest hidden
// item in the 99us non-dcn/offconv budget). New: 16px x 16ch-parts per
// block, grid 2048 = 8 blocks/CU, 32 waves/CU; coalescing line-exact.
// f32 summation order changes (16x16 vs 64x4) -- within threshold.
// offconv declared at r17/r22 local optimum (3 failed restructures);
// k_dcn at its divergent-gather floor.
// ws layout (bytes):
//   wpart bf16 [4][8][108][4096] @ 0          (28,311,552)
//   wo_a  bf16 [4][9][2][7][64][8] @ 28,311,552 (516,096)  fragment-major
//   wd_a  bf16 [4][9][64][64]    @ 28,827,648 (294,912)   [g][tap][co][cl]
//   x2    bf16 [256][4356][8]    @ 29,122,560 (17,842,176)
// total 46,964,736 B (< proven 48.3 MB)

typedef __attribute__((ext_vector_type(4))) short s16x4;
typedef __attribute__((ext_vector_type(8))) short s16x8;
typedef __attribute__((ext_vector_type(4))) float f32x4;

union S8 { s16x8 v; s16x4 h[2]; };
union S8U { s16x8 v; unsigned u[4]; };

__device__ __forceinline__ s16x8 ld8(const short* p) {
  S8 r;
  r.h[0] = *(const s16x4*)p;
  r.h[1] = *(const s16x4*)(p + 4);
  return r.v;
}

__device__ __forceinline__ unsigned short bfr(float v) {  // RNE to bf16
  unsigned u = __float_as_uint(v);
  u = (u + 0x7FFFu + ((u >> 16) & 1u)) >> 16;
  return (unsigned short)u;
}
__device__ __forceinline__ float bff(unsigned short s) {
  return __uint_as_float(((unsigned)s) << 16);
}
__device__ __forceinline__ float bf(short s) {
  return __uint_as_float(((unsigned)(unsigned short)s) << 16);
}
__device__ __forceinline__ unsigned cvtpk(float lo, float hi) {  // RNE pair
  union { __hip_bfloat162 b; unsigned u; } cv;
  cv.b = __float22bfloat162_rn(make_float2(lo, hi));
  return cv.u;
}

__global__ __launch_bounds__(256) void k_prep(
    const float* __restrict__ w_off, const float* __restrict__ w_dcn,
    short* __restrict__ wo_a, short* __restrict__ wd_a) {
  int i = blockIdx.x * 256 + threadIdx.x;
  const int n1 = 112 * 2304;  // = 258048 = 4*9*2*7*64*8
  if (i < n1) {
    // fragment-major: i = ((((part*9+tap)*2+s)*7+mt)*64 + lane)*8 + e
    int e = i & 7;
    int t1 = i >> 3;
    int lane = t1 & 63;
    int t2 = t1 >> 6;
    int mt = t2 % 7;
    int t3 = t2 / 7;
    int s = t3 & 1;
    int t4 = t3 >> 1;
    int tap = t4 % 9;
    int part = t4 / 9;
    int co = mt * 16 + (lane & 15);
    int ch = part * 64 + s * 32 + (lane >> 4) * 8 + e;
    float v = (co < 108) ? w_off[(co * 256 + ch) * 9 + tap] : 0.f;
    wo_a[i] = (short)bfr(v);
  } else {
    int j = i - n1;  // exactly 147456 remaining threads (grid 1584*256)
    int g = j / 36864, r = j % 36864;
    // layout: [g][tap][co][cl]
    int tap = r >> 12;  // r / 4096
    int q = r & 4095;
    int co = q >> 6, cl = q & 63;
    wd_a[j] = (short)bfr(w_dcn[((g * 64 + co) * 64 + cl) * 9 + tap]);
  }
}

// x -> chunked bf16 NHWC with zero halo.
// interior: thread = (b, c2, pixel); border: zero 16B slots.
__global__ __launch_bounds__(256) void k_x2(
    const float* __restrict__ x, short* __restrict__ x2) {
  int id = blockIdx.x * 256 + threadIdx.x;
  const int n1 = 8 * 32 * 4096;  // 1,048,576 interior items
  if (id < n1) {
    int pc = id & 4095;
    int c2 = (id >> 12) & 31;
    int b = id >> 17;
    int h = pc >> 6, w = pc & 63;
    const float* xp = x + ((size_t)(b * 256 + c2 * 8)) * 4096 + pc;
    short* o = x2 + ((size_t)(b * 32 + c2) * 4356 + (h + 1) * 66 + (w + 1)) * 8;
    s16x4 v0, v1;
#pragma unroll
    for (int i = 0; i < 4; ++i) {
      v0[i] = (short)bfr(xp[(size_t)i * 4096]);
      v1[i] = (short)bfr(xp[(size_t)(i + 4) * 4096]);
    }
    *(s16x4*)o = v0;
    *(s16x4*)(o + 4) = v1;
  } else {
    int j = id - n1;  // grid sized exactly: j < 256*260
    int plane = j / 260, r = j % 260;
    int h, w;
    if (r < 66) { h = 0; w = r; }
    else if (r < 132) { h = 65; w = r - 66; }
    else if (r < 196) { h = r - 131; w = 0; }
    else { h = r - 195; w = 65; }
    short* o = x2 + ((size_t)plane * 4356 + h * 66 + w) * 8;
    s16x4 z = {0, 0, 0, 0};
    *(s16x4*)o = z;
    *(s16x4*)(o + 4) = z;
  }
}

// Offset conv, bf16 MFMA, K-split by channel-quarter, XCD-pinned slices.
// Round 17/22 form: 2 output rows per block, grid 1024, 4 blocks/CU.
__global__ __launch_bounds__(256) void k_offconv(
    const short* __restrict__ x2, const short* __restrict__ wo_a,
    const float* __restrict__ b_off, short* __restrict__ wpart) {
  __shared__ short p_s[4 * 66 * 68];  // [winrow 0..3][pix 0..65][64 ch + 4 pad]
  int bi = blockIdx.x;  // 1024
  int xcd = bi & 7;
  int j = bi >> 3;                // 0..127
  int slice = xcd * 4 + (j & 3);  // 0..31, pinned to xcd
  int h0 = (j >> 2) * 2;          // 0,2,...,62
  int part = slice >> 3, b = slice & 7;
  int tid = threadIdx.x;
  int lane = tid & 63, wv = tid >> 6;
  int quad = lane >> 4, l15 = lane & 15;

  f32x4 zero4 = {0.f, 0.f, 0.f, 0.f};
  f32x4 acc[7][2];
#pragma unroll
  for (int i = 0; i < 7; ++i)
#pragma unroll
    for (int r = 0; r < 2; ++r) acc[i][r] = zero4;

  // planes for this block's 64 channels: (b*32 + part*8 + ck), ck = 0..7
  const short* x2b = x2 + (size_t)(b * 32 + part * 8) * 34848;
  // fragment-major weight base for this part: [tap][s][mt][lane][8]
  const short* wfrag = wo_a + (size_t)part * 64512 + lane * 8;

  // Stage the 4-row x 66-col window once: 2112 x 16B chunks (8.25/thread).
  for (int it = tid; it < 2112; it += 256) {
    int ck = it / 264;
    int rp = it - ck * 264;  // rp = winrow*66 + pix
    const short* src = x2b + (size_t)ck * 34848 + ((size_t)h0 * 66 + rp) * 8;
    S8 v;
    v.v = *(const s16x8*)src;  // 16B aligned
    short* dst = &p_s[rp * 68 + ck * 8];
    *(s16x4*)dst = v.h[0];
    *(s16x4*)(dst + 4) = v.h[1];
  }
  __syncthreads();

  int nb = 16 * wv + l15;  // output column this lane owns (B-fragment row)
#pragma unroll
  for (int tap = 0; tap < 9; ++tap) {
    int ky = tap / 3, kx = tap % 3;
#pragma unroll
    for (int s = 0; s < 2; ++s) {
      int k0 = 32 * s + quad * 8;
      const short* wb = wfrag + (size_t)(tap * 2 + s) * 3584;
      s16x8 af[7];
#pragma unroll
      for (int mt = 0; mt < 7; ++mt)
        af[mt] = *(const s16x8*)(wb + (size_t)mt * 512);
#pragma unroll
      for (int r = 0; r < 2; ++r) {
        // output row h0+r, tap (ky,kx): padded (h0+r+ky, nb+kx) = winrow r+ky
        s16x8 bf_f = ld8(&p_s[((r + ky) * 66 + nb + kx) * 68 + k0]);
#pragma unroll
        for (int mt = 0; mt < 7; ++mt)
          acc[mt][r] =
              __builtin_amdgcn_mfma_f32_16x16x32_bf16(af[mt], bf_f, acc[mt][r], 0, 0, 0);
      }
    }
  }

  short* wp = wpart + ((size_t)part * 8 + b) * 108 * 4096;
#pragma unroll
  for (int mt = 0; mt < 7; ++mt) {
#pragma unroll
    for (int rr = 0; rr < 2; ++rr) {
#pragma unroll
      for (int r = 0; r < 4; ++r) {
        int co = 16 * mt + quad * 4 + r;
        if (co < 108) {
          float v = acc[mt][rr][r] + (part == 0 ? b_off[co] : 0.f);
          wp[(size_t)co * 4096 + (h0 + rr) * 64 + nb] = (short)bfr(v);
        }
      }
    }
  }
}

// DCN, bf16 MFMA, XCD-pinned (b,g) groups.
// Round 22 form: r17 structure (1-row, grid 2048, wlds double-buffered
// staging, 1 barrier/tap, corner prefetch) + cvt_pk pair rounding.
__global__ __launch_bounds__(256) void k_dcn(
    const short* __restrict__ x2, const short* __restrict__ wpart,
    const short* __restrict__ wd_a, const float* __restrict__ b_dcn,
    float* __restrict__ dcn) {
  __shared__ float4 prm[9][64];      // (py, pxf, m, -) per (tap, px)
  __shared__ short wlds[2][64][72];  // [buf][co][64k + 8 pad]

  int bi = blockIdx.x;  // 2048
  int xcd = bi & 7;
  int j = bi >> 3;
  int grp = xcd * 4 + (j & 3);  // 0..31, pinned to xcd
  int h = j >> 2;               // 0..63
  int b = grp >> 2, g = grp & 3;
  int tid = threadIdx.x;
  int lane = tid & 63, wv = tid >> 6;
  int quad = lane >> 4, l15 = lane & 15;
  int px = 16 * wv + l15;  // pixel this lane samples AND owns as output column

  f32x4 zero4 = {0.f, 0.f, 0.f, 0.f};
  f32x4 acc[4];
#pragma unroll
  for (int i = 0; i < 4; ++i) acc[i] = zero4;

  const short* x2g = x2 + (size_t)(b * 32 + g * 8) * 34848;
  const short* plA = x2g + (size_t)quad * 34848;        // chans 8q..8q+7  (s=0)
  const short* plB = x2g + (size_t)(quad + 4) * 34848;  // chans 32+8q..+7 (s=1)
  const short* wd_g = wd_a + (size_t)g * 36864;         // [tap][co][64]

  // weight staging role: thread stages 32B of the tap slice (coalesced)
  int co_w = tid >> 2, kp_w = (tid & 3) * 16;

  // ---- Prologue: stage tap-0 weights + offset/mask params; one barrier ----
  {
    const short* wsrc = wd_g + co_w * 64 + kp_w;
    s16x8 w0 = *(const s16x8*)wsrc;
    s16x8 w1 = *(const s16x8*)(wsrc + 8);
    *(s16x8*)&wlds[0][co_w][kp_w] = w0;
    *(s16x8*)&wlds[0][co_w][kp_w + 8] = w1;
  }
  for (int i = tid; i < 576; i += 256) {
    int c = i >> 6, pxa = i & 63;
    int sp = h * 64 + pxa;
    int co_y = (g * 9 + c) * 2;
    float oy = 0.f, ox = 0.f, mz = 0.f;
#pragma unroll
    for (int p4 = 0; p4 < 4; ++p4) {
      const short* wp = wpart + ((size_t)p4 * 8 + b) * 108 * 4096;
      oy += bff((unsigned short)wp[(size_t)co_y * 4096 + sp]);
      ox += bff((unsigned short)wp[(size_t)(co_y + 1) * 4096 + sp]);
      mz += bff((unsigned short)wp[(size_t)(72 + g * 9 + c) * 4096 + sp]);
    }
    float m = 1.f / (1.f + __expf(-mz));
    float py = (float)h + (float)(c / 3 - 1) + oy;
    float pxf = (float)pxa + (float)(c % 3 - 1) + ox;
    prm[c][pxa] = make_float4(py, pxf, m, 0.f);
  }
  __syncthreads();  // covers prm + wlds[0]

  // corner registers, double-buffered across taps
  s16x8 cA[2][4], cB[2][4];
  float4 wts[2];

  auto stage = [&](int c, int st) {
    float4 pr = prm[c][px];
    float py = pr.x, pxf = pr.y, m = pr.z;
    float y0 = floorf(py), x0 = floorf(pxf);
    float wy1 = py - y0, wy0 = 1.f - wy1;
    float wx1 = pxf - x0, wx0 = 1.f - wx1;
    int y0i = (int)y0, x0i = (int)x0;
    int y1i = y0i + 1, x1i = x0i + 1;
    bool vy0 = (y0i >= 0) & (y0i < 64), vy1 = (y1i >= 0) & (y1i < 64);
    bool vx0 = (x0i >= 0) & (x0i < 64), vx1 = (x1i >= 0) & (x1i < 64);
    int cy0 = min(max(y0i, 0), 63) + 1, cy1 = min(max(y1i, 0), 63) + 1;
    int cx0 = min(max(x0i, 0), 63) + 1, cx1 = min(max(x1i, 0), 63) + 1;
    int i00 = cy0 * 66 + cx0, i01 = cy0 * 66 + cx1;
    int i10 = cy1 * 66 + cx0, i11 = cy1 * 66 + cx1;
    wts[st] = make_float4((vy0 && vx0) ? wy0 * wx0 * m : 0.f,
                          (vy0 && vx1) ? wy0 * wx1 * m : 0.f,
                          (vy1 && vx0) ? wy1 * wx0 * m : 0.f,
                          (vy1 && vx1) ? wy1 * wx1 * m : 0.f);
    cA[st][0] = *(const s16x8*)(plA + (size_t)i00 * 8);  // 16B aligned
    cA[st][1] = *(const s16x8*)(plA + (size_t)i01 * 8);
    cA[st][2] = *(const s16x8*)(plA + (size_t)i10 * 8);
    cA[st][3] = *(const s16x8*)(plA + (size_t)i11 * 8);
    cB[st][0] = *(const s16x8*)(plB + (size_t)i00 * 8);
    cB[st][1] = *(const s16x8*)(plB + (size_t)i01 * 8);
    cB[st][2] = *(const s16x8*)(plB + (size_t)i10 * 8);
    cB[st][3] = *(const s16x8*)(plB + (size_t)i11 * 8);
  };

  stage(0, 0);
#pragma unroll
  for (int c = 0; c < 9; ++c) {
    int cur = c & 1;                   // compile-time after unroll
    // issue next-tap weight loads (coalesced) + corner gathers, all in flight
    s16x8 wn0, wn1;
    if (c < 8) {
      const short* wsrc = wd_g + (size_t)(c + 1) * 4096 + co_w * 64 + kp_w;
      wn0 = *(const s16x8*)wsrc;
      wn1 = *(const s16x8*)(wsrc + 8);
      stage(c + 1, cur ^ 1);
    }

    float4 w = wts[cur];
    // bilinear combine (same math/order as r17), cvt_pk pair rounding
    S8U bf0, bf1;
#pragma unroll
    for (int i2 = 0; i2 < 4; ++i2) {
      int e0 = 2 * i2, e1 = 2 * i2 + 1;
      float vA0 = w.x * bf(cA[cur][0][e0]) + w.y * bf(cA[cur][1][e0]) +
                  w.z * bf(cA[cur][2][e0]) + w.w * bf(cA[cur][3][e0]);
      float vA1 = w.x * bf(cA[cur][0][e1]) + w.y * bf(cA[cur][1][e1]) +
                  w.z * bf(cA[cur][2][e1]) + w.w * bf(cA[cur][3][e1]);
      float vB0 = w.x * bf(cB[cur][0][e0]) + w.y * bf(cB[cur][1][e0]) +
                  w.z * bf(cB[cur][2][e0]) + w.w * bf(cB[cur][3][e0]);
      float vB1 = w.x * bf(cB[cur][0][e1]) + w.y * bf(cB[cur][1][e1]) +
                  w.z * bf(cB[cur][2][e1]) + w.w * bf(cB[cur][3][e1]);
      bf0.u[i2] = cvtpk(vA0, vA1);
      bf1.u[i2] = cvtpk(vB0, vB1);
    }

#pragma unroll
    for (int mt = 0; mt < 4; ++mt) {  // s = 0: k0 = quad*8
      s16x8 af = *(const s16x8*)&wlds[cur][16 * mt + l15][quad * 8];
      acc[mt] = __builtin_amdgcn_mfma_f32_16x16x32_bf16(af, bf0.v, acc[mt], 0, 0, 0);
    }
#pragma unroll
    for (int mt = 0; mt < 4; ++mt) {  // s = 1: k0 = 32 + quad*8
      s16x8 af = *(const s16x8*)&wlds[cur][16 * mt + l15][32 + quad * 8];
      acc[mt] = __builtin_amdgcn_mfma_f32_16x16x32_bf16(af, bf1.v, acc[mt], 0, 0, 0);
    }

    if (c < 8) {
      // write next tap's weights; prior readers of this buffer passed the
      // previous iteration's barrier already.
      *(s16x8*)&wlds[cur ^ 1][co_w][kp_w] = wn0;
      *(s16x8*)&wlds[cur ^ 1][co_w][kp_w + 8] = wn1;
      __syncthreads();
    }
  }

  int nb = px;
#pragma unroll
  for (int mt = 0; mt < 4; ++mt) {
#pragma unroll
    for (int r = 0; r < 4; ++r) {
      int co = 16 * mt + quad * 4 + r;
      dcn[(((size_t)b * 256 + g * 64 + co) * 64 + h) * 64 + nb] =
          acc[mt][r] + b_dcn[g * 64 + co];
    }
  }
}

// LayerNorm over C + sigmoid + gate. dcn == out (in-place safe).
// Round 25: 16px x 16ch-parts per block, grid 2048 = 8 blocks/CU
// (32 waves/CU; was 512 blocks = 2/CU = 25% occupancy cap on a ~100MB
// memory-bound kernel). Coalescing line-exact (4x64B segments/wave-load).
__global__ __launch_bounds__(256) void k_ln(
    const float* __restrict__ dcn, const float* __restrict__ x,
    const float* __restrict__ gamma, const float* __restrict__ beta,
    float* __restrict__ out) {
  __shared__ float red_s[16][16];
  __shared__ float red_q[16][16];
  int px = threadIdx.x & 15;
  int part = threadIdx.x >> 4;   // 0..15
  int p = blockIdx.x * 16 + px;  // 32768 pixels, grid 2048
  int b = p >> 12, hw = p & 4095;
  const float* ob = dcn + (size_t)b * 256 * 4096 + hw;
  const float* xb = x + (size_t)b * 256 * 4096 + hw;
  float* yb = out + (size_t)b * 256 * 4096 + hw;
  int c0 = part * 16;
  float v[16];
  float s = 0.f, s2 = 0.f;
#pragma unroll
  for (int i = 0; i < 16; ++i) {
    v[i] = ob[(size_t)(c0 + i) * 4096];
    s += v[i];
    s2 += v[i] * v[i];
  }
  red_s[part][px] = s;
  red_q[part][px] = s2;
  __syncthreads();
  float S = 0.f, S2 = 0.f;
#pragma unroll
  for (int p2 = 0; p2 < 16; ++p2) {
    S += red_s[p2][px];
    S2 += red_q[p2][px];
  }
  float mu = S * (1.f / 256.f);
  float var = S2 * (1.f / 256.f) - mu * mu;
  float rs = rsqrtf(var + 1e-5f);
#pragma unroll
  for (int i = 0; i < 16; ++i) {
    int c = c0 + i;
    float nrm = (v[i] - mu) * rs * gamma[c] + beta[c];
    float attn = 1.f / (1.f + __expf(-nrm));
    yb[(size_t)c * 4096] = xb[(size_t)c * 4096] * attn;
  }
}

extern "C" void kernel_launch(void* const* d_in, const int* in_sizes, int n_in,
                              void* d_out, int out_size, void* d_ws,
                              size_t ws_size, hipStream_t stream) {
  const float* x = (const float*)d_in[0];
  const float* w_off = (const float*)d_in[1];
  const float* b_off = (const float*)d_in[2];
  const float* w_dcn = (const float*)d_in[3];
  const float* b_dcn = (const float*)d_in[4];
  const float* gamma = (const float*)d_in[5];
  const float* beta = (const float*)d_in[6];
  float* out = (float*)d_out;
  char* wsb = (char*)d_ws;

  short* wpart = (short*)wsb;              // 28,311,552 B
  short* wo_a = (short*)(wsb + 28311552);  // 516,096 B
  short* wd_a = (short*)(wsb + 28827648);  // 294,912 B
  short* x2 = (short*)(wsb + 29122560);    // 17,842,176 B
  float* dcnb = out;                       // d_out doubles as dcn scratch

  k_prep<<<1584, 256, 0, stream>>>(w_off, w_dcn, wo_a, wd_a);
  k_x2<<<4356, 256, 0, stream>>>(x, x2);
  k_offconv<<<1024, 256, 0, stream>>>(x2, wo_a, b_off, wpart);
  k_dcn<<<2048, 256, 0, stream>>>(x2, wpart, wd_a, b_dcn, dcnb);
  k_ln<<<2048, 256, 0, stream>>>(dcnb, x, gamma, beta, out);
}

// Round 18
// 192.765 us; speedup vs baseline: 1.0540x; 1.0486x over previous
//
#include <hip/hip_runtime.h>
#include <hip/hip_bf16.h>
#include <math.h>

// B=8, C=256, H=W=64, G=4, K=3, KK=9, Cg=64
// Round 27 == Round 26 resubmitted (bench infra failed twice; source is
// byte-identical to the round-22 build that measured 193.5us).
// k_dcn: r17 structure + cvt_pk rounding (6 restructures -> local optimum).
// k_offconv: 2-row blocks, fragment-major weights (3 restructures -> opt).
// k_ln: 64px/4part one-pass. ~60us of total is harness-side.
// ws layout (bytes):
//   wpart bf16 [4][8][108][4096] @ 0          (28,311,552)
//   wo_a  bf16 [4][9][2][7][64][8] @ 28,311,552 (516,096)  fragment-major
//   wd_a  bf16 [4][9][64][64]    @ 28,827,648 (294,912)   [g][tap][co][cl]
//   x2    bf16 [256][4356][8]    @ 29,122,560 (17,842,176)
// total 46,964,736 B (< proven 48.3 MB)

typedef __attribute__((ext_vector_type(4))) short s16x4;
typedef __attribute__((ext_vector_type(8))) short s16x8;
typedef __attribute__((ext_vector_type(4))) float f32x4;

union S8 { s16x8 v; s16x4 h[2]; };
union S8U { s16x8 v; unsigned u[4]; };

__device__ __forceinline__ s16x8 ld8(const short* p) {
  S8 r;
  r.h[0] = *(const s16x4*)p;
  r.h[1] = *(const s16x4*)(p + 4);
  return r.v;
}

__device__ __forceinline__ unsigned short bfr(float v) {  // RNE to bf16
  unsigned u = __float_as_uint(v);
  u = (u + 0x7FFFu + ((u >> 16) & 1u)) >> 16;
  return (unsigned short)u;
}
__device__ __forceinline__ float bff(unsigned short s) {
  return __uint_as_float(((unsigned)s) << 16);
}
__device__ __forceinline__ float bf(short s) {
  return __uint_as_float(((unsigned)(unsigned short)s) << 16);
}
__device__ __forceinline__ unsigned cvtpk(float lo, float hi) {  // RNE pair
  union { __hip_bfloat162 b; unsigned u; } cv;
  cv.b = __float22bfloat162_rn(make_float2(lo, hi));
  return cv.u;
}

__global__ __launch_bounds__(256) void k_prep(
    const float* __restrict__ w_off, const float* __restrict__ w_dcn,
    short* __restrict__ wo_a, short* __restrict__ wd_a) {
  int i = blockIdx.x * 256 + threadIdx.x;
  const int n1 = 112 * 2304;  // = 258048 = 4*9*2*7*64*8
  if (i < n1) {
    // fragment-major: i = ((((part*9+tap)*2+s)*7+mt)*64 + lane)*8 + e
    int e = i & 7;
    int t1 = i >> 3;
    int lane = t1 & 63;
    int t2 = t1 >> 6;
    int mt = t2 % 7;
    int t3 = t2 / 7;
    int s = t3 & 1;
    int t4 = t3 >> 1;
    int tap = t4 % 9;
    int part = t4 / 9;
    int co = mt * 16 + (lane & 15);
    int ch = part * 64 + s * 32 + (lane >> 4) * 8 + e;
    float v = (co < 108) ? w_off[(co * 256 + ch) * 9 + tap] : 0.f;
    wo_a[i] = (short)bfr(v);
  } else {
    int j = i - n1;  // exactly 147456 remaining threads (grid 1584*256)
    int g = j / 36864, r = j % 36864;
    // layout: [g][tap][co][cl]
    int tap = r >> 12;  // r / 4096
    int q = r & 4095;
    int co = q >> 6, cl = q & 63;
    wd_a[j] = (short)bfr(w_dcn[((g * 64 + co) * 64 + cl) * 9 + tap]);
  }
}

// x -> chunked bf16 NHWC with zero halo.
// interior: thread = (b, c2, pixel); border: zero 16B slots.
__global__ __launch_bounds__(256) void k_x2(
    const float* __restrict__ x, short* __restrict__ x2) {
  int id = blockIdx.x * 256 + threadIdx.x;
  const int n1 = 8 * 32 * 4096;  // 1,048,576 interior items
  if (id < n1) {
    int pc = id & 4095;
    int c2 = (id >> 12) & 31;
    int b = id >> 17;
    int h = pc >> 6, w = pc & 63;
    const float* xp = x + ((size_t)(b * 256 + c2 * 8)) * 4096 + pc;
    short* o = x2 + ((size_t)(b * 32 + c2) * 4356 + (h + 1) * 66 + (w + 1)) * 8;
    s16x4 v0, v1;
#pragma unroll
    for (int i = 0; i < 4; ++i) {
      v0[i] = (short)bfr(xp[(size_t)i * 4096]);
      v1[i] = (short)bfr(xp[(size_t)(i + 4) * 4096]);
    }
    *(s16x4*)o = v0;
    *(s16x4*)(o + 4) = v1;
  } else {
    int j = id - n1;  // grid sized exactly: j < 256*260
    int plane = j / 260, r = j % 260;
    int h, w;
    if (r < 66) { h = 0; w = r; }
    else if (r < 132) { h = 65; w = r - 66; }
    else if (r < 196) { h = r - 131; w = 0; }
    else { h = r - 195; w = 65; }
    short* o = x2 + ((size_t)plane * 4356 + h * 66 + w) * 8;
    s16x4 z = {0, 0, 0, 0};
    *(s16x4*)o = z;
    *(s16x4*)(o + 4) = z;
  }
}

// Offset conv, bf16 MFMA, K-split by channel-quarter, XCD-pinned slices.
// Round 17/22 form: 2 output rows per block, grid 1024, 4 blocks/CU.
__global__ __launch_bounds__(256) void k_offconv(
    const short* __restrict__ x2, const short* __restrict__ wo_a,
    const float* __restrict__ b_off, short* __restrict__ wpart) {
  __shared__ short p_s[4 * 66 * 68];  // [winrow 0..3][pix 0..65][64 ch + 4 pad]
  int bi = blockIdx.x;  // 1024
  int xcd = bi & 7;
  int j = bi >> 3;                // 0..127
  int slice = xcd * 4 + (j & 3);  // 0..31, pinned to xcd
  int h0 = (j >> 2) * 2;          // 0,2,...,62
  int part = slice >> 3, b = slice & 7;
  int tid = threadIdx.x;
  int lane = tid & 63, wv = tid >> 6;
  int quad = lane >> 4, l15 = lane & 15;

  f32x4 zero4 = {0.f, 0.f, 0.f, 0.f};
  f32x4 acc[7][2];
#pragma unroll
  for (int i = 0; i < 7; ++i)
#pragma unroll
    for (int r = 0; r < 2; ++r) acc[i][r] = zero4;

  // planes for this block's 64 channels: (b*32 + part*8 + ck), ck = 0..7
  const short* x2b = x2 + (size_t)(b * 32 + part * 8) * 34848;
  // fragment-major weight base for this part: [tap][s][mt][lane][8]
  const short* wfrag = wo_a + (size_t)part * 64512 + lane * 8;

  // Stage the 4-row x 66-col window once: 2112 x 16B chunks (8.25/thread).
  for (int it = tid; it < 2112; it += 256) {
    int ck = it / 264;
    int rp = it - ck * 264;  // rp = winrow*66 + pix
    const short* src = x2b + (size_t)ck * 34848 + ((size_t)h0 * 66 + rp) * 8;
    S8 v;
    v.v = *(const s16x8*)src;  // 16B aligned
    short* dst = &p_s[rp * 68 + ck * 8];
    *(s16x4*)dst = v.h[0];
    *(s16x4*)(dst + 4) = v.h[1];
  }
  __syncthreads();

  int nb = 16 * wv + l15;  // output column this lane owns (B-fragment row)
#pragma unroll
  for (int tap = 0; tap < 9; ++tap) {
    int ky = tap / 3, kx = tap % 3;
#pragma unroll
    for (int s = 0; s < 2; ++s) {
      int k0 = 32 * s + quad * 8;
      const short* wb = wfrag + (size_t)(tap * 2 + s) * 3584;
      s16x8 af[7];
#pragma unroll
      for (int mt = 0; mt < 7; ++mt)
        af[mt] = *(const s16x8*)(wb + (size_t)mt * 512);
#pragma unroll
      for (int r = 0; r < 2; ++r) {
        // output row h0+r, tap (ky,kx): padded (h0+r+ky, nb+kx) = winrow r+ky
        s16x8 bf_f = ld8(&p_s[((r + ky) * 66 + nb + kx) * 68 + k0]);
#pragma unroll
        for (int mt = 0; mt < 7; ++mt)
          acc[mt][r] =
              __builtin_amdgcn_mfma_f32_16x16x32_bf16(af[mt], bf_f, acc[mt][r], 0, 0, 0);
      }
    }
  }

  short* wp = wpart + ((size_t)part * 8 + b) * 108 * 4096;
#pragma unroll
  for (int mt = 0; mt < 7; ++mt) {
#pragma unroll
    for (int rr = 0; rr < 2; ++rr) {
#pragma unroll
      for (int r = 0; r < 4; ++r) {
        int co = 16 * mt + quad * 4 + r;
        if (co < 108) {
          float v = acc[mt][rr][r] + (part == 0 ? b_off[co] : 0.f);
          wp[(size_t)co * 4096 + (h0 + rr) * 64 + nb] = (short)bfr(v);
        }
      }
    }
  }
}

// DCN, bf16 MFMA, XCD-pinned (b,g) groups.
// Round 22 form: r17 structure (1-row, grid 2048, wlds double-buffered
// staging, 1 barrier/tap, corner prefetch) + cvt_pk pair rounding.
__global__ __launch_bounds__(256) void k_dcn(
    const short* __restrict__ x2, const short* __restrict__ wpart,
    const short* __restrict__ wd_a, const float* __restrict__ b_dcn,
    float* __restrict__ dcn) {
  __shared__ float4 prm[9][64];      // (py, pxf, m, -) per (tap, px)
  __shared__ short wlds[2][64][72];  // [buf][co][64k + 8 pad]

  int bi = blockIdx.x;  // 2048
  int xcd = bi & 7;
  int j = bi >> 3;
  int grp = xcd * 4 + (j & 3);  // 0..31, pinned to xcd
  int h = j >> 2;               // 0..63
  int b = grp >> 2, g = grp & 3;
  int tid = threadIdx.x;
  int lane = tid & 63, wv = tid >> 6;
  int quad = lane >> 4, l15 = lane & 15;
  int px = 16 * wv + l15;  // pixel this lane samples AND owns as output column

  f32x4 zero4 = {0.f, 0.f, 0.f, 0.f};
  f32x4 acc[4];
#pragma unroll
  for (int i = 0; i < 4; ++i) acc[i] = zero4;

  const short* x2g = x2 + (size_t)(b * 32 + g * 8) * 34848;
  const short* plA = x2g + (size_t)quad * 34848;        // chans 8q..8q+7  (s=0)
  const short* plB = x2g + (size_t)(quad + 4) * 34848;  // chans 32+8q..+7 (s=1)
  const short* wd_g = wd_a + (size_t)g * 36864;         // [tap][co][64]

  // weight staging role: thread stages 32B of the tap slice (coalesced)
  int co_w = tid >> 2, kp_w = (tid & 3) * 16;

  // ---- Prologue: stage tap-0 weights + offset/mask params; one barrier ----
  {
    const short* wsrc = wd_g + co_w * 64 + kp_w;
    s16x8 w0 = *(const s16x8*)wsrc;
    s16x8 w1 = *(const s16x8*)(wsrc + 8);
    *(s16x8*)&wlds[0][co_w][kp_w] = w0;
    *(s16x8*)&wlds[0][co_w][kp_w + 8] = w1;
  }
  for (int i = tid; i < 576; i += 256) {
    int c = i >> 6, pxa = i & 63;
    int sp = h * 64 + pxa;
    int co_y = (g * 9 + c) * 2;
    float oy = 0.f, ox = 0.f, mz = 0.f;
#pragma unroll
    for (int p4 = 0; p4 < 4; ++p4) {
      const short* wp = wpart + ((size_t)p4 * 8 + b) * 108 * 4096;
      oy += bff((unsigned short)wp[(size_t)co_y * 4096 + sp]);
      ox += bff((unsigned short)wp[(size_t)(co_y + 1) * 4096 + sp]);
      mz += bff((unsigned short)wp[(size_t)(72 + g * 9 + c) * 4096 + sp]);
    }
    float m = 1.f / (1.f + __expf(-mz));
    float py = (float)h + (float)(c / 3 - 1) + oy;
    float pxf = (float)pxa + (float)(c % 3 - 1) + ox;
    prm[c][pxa] = make_float4(py, pxf, m, 0.f);
  }
  __syncthreads();  // covers prm + wlds[0]

  // corner registers, double-buffered across taps
  s16x8 cA[2][4], cB[2][4];
  float4 wts[2];

  auto stage = [&](int c, int st) {
    float4 pr = prm[c][px];
    float py = pr.x, pxf = pr.y, m = pr.z;
    float y0 = floorf(py), x0 = floorf(pxf);
    float wy1 = py - y0, wy0 = 1.f - wy1;
    float wx1 = pxf - x0, wx0 = 1.f - wx1;
    int y0i = (int)y0, x0i = (int)x0;
    int y1i = y0i + 1, x1i = x0i + 1;
    bool vy0 = (y0i >= 0) & (y0i < 64), vy1 = (y1i >= 0) & (y1i < 64);
    bool vx0 = (x0i >= 0) & (x0i < 64), vx1 = (x1i >= 0) & (x1i < 64);
    int cy0 = min(max(y0i, 0), 63) + 1, cy1 = min(max(y1i, 0), 63) + 1;
    int cx0 = min(max(x0i, 0), 63) + 1, cx1 = min(max(x1i, 0), 63) + 1;
    int i00 = cy0 * 66 + cx0, i01 = cy0 * 66 + cx1;
    int i10 = cy1 * 66 + cx0, i11 = cy1 * 66 + cx1;
    wts[st] = make_float4((vy0 && vx0) ? wy0 * wx0 * m : 0.f,
                          (vy0 && vx1) ? wy0 * wx1 * m : 0.f,
                          (vy1 && vx0) ? wy1 * wx0 * m : 0.f,
                          (vy1 && vx1) ? wy1 * wx1 * m : 0.f);
    cA[st][0] = *(const s16x8*)(plA + (size_t)i00 * 8);  // 16B aligned
    cA[st][1] = *(const s16x8*)(plA + (size_t)i01 * 8);
    cA[st][2] = *(const s16x8*)(plA + (size_t)i10 * 8);
    cA[st][3] = *(const s16x8*)(plA + (size_t)i11 * 8);
    cB[st][0] = *(const s16x8*)(plB + (size_t)i00 * 8);
    cB[st][1] = *(const s16x8*)(plB + (size_t)i01 * 8);
    cB[st][2] = *(const s16x8*)(plB + (size_t)i10 * 8);
    cB[st][3] = *(const s16x8*)(plB + (size_t)i11 * 8);
  };

  stage(0, 0);
#pragma unroll
  for (int c = 0; c < 9; ++c) {
    int cur = c & 1;                   // compile-time after unroll
    // issue next-tap weight loads (coalesced) + corner gathers, all in flight
    s16x8 wn0, wn1;
    if (c < 8) {
      const short* wsrc = wd_g + (size_t)(c + 1) * 4096 + co_w * 64 + kp_w;
      wn0 = *(const s16x8*)wsrc;
      wn1 = *(const s16x8*)(wsrc + 8);
      stage(c + 1, cur ^ 1);
    }

    float4 w = wts[cur];
    // bilinear combine (same math/order as r17), cvt_pk pair rounding
    S8U bf0, bf1;
#pragma unroll
    for (int i2 = 0; i2 < 4; ++i2) {
      int e0 = 2 * i2, e1 = 2 * i2 + 1;
      float vA0 = w.x * bf(cA[cur][0][e0]) + w.y * bf(cA[cur][1][e0]) +
                  w.z * bf(cA[cur][2][e0]) + w.w * bf(cA[cur][3][e0]);
      float vA1 = w.x * bf(cA[cur][0][e1]) + w.y * bf(cA[cur][1][e1]) +
                  w.z * bf(cA[cur][2][e1]) + w.w * bf(cA[cur][3][e1]);
      float vB0 = w.x * bf(cB[cur][0][e0]) + w.y * bf(cB[cur][1][e0]) +
                  w.z * bf(cB[cur][2][e0]) + w.w * bf(cB[cur][3][e0]);
      float vB1 = w.x * bf(cB[cur][0][e1]) + w.y * bf(cB[cur][1][e1]) +
                  w.z * bf(cB[cur][2][e1]) + w.w * bf(cB[cur][3][e1]);
      bf0.u[i2] = cvtpk(vA0, vA1);
      bf1.u[i2] = cvtpk(vB0, vB1);
    }

#pragma unroll
    for (int mt = 0; mt < 4; ++mt) {  // s = 0: k0 = quad*8
      s16x8 af = *(const s16x8*)&wlds[cur][16 * mt + l15][quad * 8];
      acc[mt] = __builtin_amdgcn_mfma_f32_16x16x32_bf16(af, bf0.v, acc[mt], 0, 0, 0);
    }
#pragma unroll
    for (int mt = 0; mt < 4; ++mt) {  // s = 1: k0 = 32 + quad*8
      s16x8 af = *(const s16x8*)&wlds[cur][16 * mt + l15][32 + quad * 8];
      acc[mt] = __builtin_amdgcn_mfma_f32_16x16x32_bf16(af, bf1.v, acc[mt], 0, 0, 0);
    }

    if (c < 8) {
      // write next tap's weights; prior readers of this buffer passed the
      // previous iteration's barrier already.
      *(s16x8*)&wlds[cur ^ 1][co_w][kp_w] = wn0;
      *(s16x8*)&wlds[cur ^ 1][co_w][kp_w + 8] = wn1;
      __syncthreads();
    }
  }

  int nb = px;
#pragma unroll
  for (int mt = 0; mt < 4; ++mt) {
#pragma unroll
    for (int r = 0; r < 4; ++r) {
      int co = 16 * mt + quad * 4 + r;
      dcn[(((size_t)b * 256 + g * 64 + co) * 64 + h) * 64 + nb] =
          acc[mt][r] + b_dcn[g * 64 + co];
    }
  }
}

// LayerNorm over C + sigmoid + gate. dcn == out (in-place safe).
// Round 17 form: one-pass, 64 channel values cached in registers.
__global__ __launch_bounds__(256) void k_ln(
    const float* __restrict__ dcn, const float* __restrict__ x,
    const float* __restrict__ gamma, const float* __restrict__ beta,
    float* __restrict__ out) {
  __shared__ float red_s[4][64];
  __shared__ float red_q[4][64];
  int px = threadIdx.x & 63;
  int part = threadIdx.x >> 6;
  int p = blockIdx.x * 64 + px;  // 32768 pixels
  int b = p >> 12, hw = p & 4095;
  const float* ob = dcn + (size_t)b * 256 * 4096 + hw;
  const float* xb = x + (size_t)b * 256 * 4096 + hw;
  float* yb = out + (size_t)b * 256 * 4096 + hw;
  int c0 = part * 64;
  float v[64];
  float s = 0.f, s2 = 0.f;
#pragma unroll
  for (int i = 0; i < 64; ++i) {
    v[i] = ob[(c0 + i) * 4096];
    s += v[i];
    s2 += v[i] * v[i];
  }
  red_s[part][px] = s;
  red_q[part][px] = s2;
  __syncthreads();
  s = red_s[0][px] + red_s[1][px] + red_s[2][px] + red_s[3][px];
  s2 = red_q[0][px] + red_q[1][px] + red_q[2][px] + red_q[3][px];
  float mu = s * (1.f / 256.f);
  float var = s2 * (1.f / 256.f) - mu * mu;
  float rs = rsqrtf(var + 1e-5f);
#pragma unroll
  for (int i = 0; i < 64; ++i) {
    int c = c0 + i;
    float nrm = (v[i] - mu) * rs * gamma[c] + beta[c];
    float attn = 1.f / (1.f + __expf(-nrm));
    yb[c * 4096] = xb[c * 4096] * attn;
  }
}

extern "C" void kernel_launch(void* const* d_in, const int* in_sizes, int n_in,
                              void* d_out, int out_size, void* d_ws,
                              size_t ws_size, hipStream_t stream) {
  const float* x = (const float*)d_in[0];
  const float* w_off = (const float*)d_in[1];
  const float* b_off = (const float*)d_in[2];
  const float* w_dcn = (const float*)d_in[3];
  const float* b_dcn = (const float*)d_in[4];
  const float* gamma = (const float*)d_in[5];
  const float* beta = (const float*)d_in[6];
  float* out = (float*)d_out;
  char* wsb = (char*)d_ws;

  short* wpart = (short*)wsb;              // 28,311,552 B
  short* wo_a = (short*)(wsb + 28311552);  // 516,096 B
  short* wd_a = (short*)(wsb + 28827648);  // 294,912 B
  short* x2 = (short*)(wsb + 29122560);    // 17,842,176 B
  float* dcnb = out;                       // d_out doubles as dcn scratch

  k_prep<<<1584, 256, 0, stream>>>(w_off, w_dcn, wo_a, wd_a);
  k_x2<<<4356, 256, 0, stream>>>(x, x2);
  k_offconv<<<1024, 256, 0, stream>>>(x2, wo_a, b_off, wpart);
  k_dcn<<<2048, 256, 0, stream>>>(x2, wpart, wd_a, b_dcn, dcnb);
  k_ln<<<512, 256, 0, stream>>>(dcnb, x, gamma, beta, out);
}